// Round 1
// baseline (683.553 us; speedup 1.0000x reference)
//
#include <hip/hip_runtime.h>
#include <hip/hip_bf16.h>

// ---------- types ----------
typedef short bf16x8 __attribute__((ext_vector_type(8)));   // 8 bf16 in 4 VGPRs
typedef float f32x4  __attribute__((ext_vector_type(4)));

// RNE float->bf16 (inputs are finite normals; NaN path not needed)
__device__ __forceinline__ short f2bf(float f) {
    union { float f; unsigned u; } a; a.f = f;
    unsigned r = a.u + 0x7fffu + ((a.u >> 16) & 1u);
    return (short)(r >> 16);
}

__device__ __forceinline__ void gload16(const void* g, void* l) {
    __builtin_amdgcn_global_load_lds(
        (const __attribute__((address_space(1))) unsigned int*)g,
        (__attribute__((address_space(3))) unsigned int*)l,
        16 /*bytes, literal*/, 0, 0);
}

// ---------- prep 1: x f32 -> bf16 ----------
__global__ __launch_bounds__(256) void cvt_x(const float* __restrict__ x,
                                             short* __restrict__ xb, long n) {
    const long t = (long)blockIdx.x * blockDim.x + threadIdx.x;
    const long stride = (long)gridDim.x * blockDim.x;
    for (long i = t * 4; i < n; i += stride * 4) {
        float4 v = *(const float4*)&x[i];
        short4 o;
        o.x = f2bf(v.x); o.y = f2bf(v.y); o.z = f2bf(v.z); o.w = f2bf(v.w);
        *(short4*)&xb[i] = o;
    }
}

// ---------- prep 2: W = Wm + exp(.5u)*eps*exp(.5v), bf16, TRANSPOSED -> Wt[M][N] ----------
__global__ __launch_bounds__(256) void build_wt(const float* __restrict__ Wm,
                                                const float* __restrict__ eps,
                                                const float* __restrict__ Wu,
                                                const float* __restrict__ Wv,
                                                short* __restrict__ Wt,
                                                int N, int M) {
    __shared__ __align__(16) short tile[64][68];   // +4 pad: phase-2 column reads spread banks
    __shared__ float su[64], sv[64];
    const int n0 = blockIdx.y * 64, m0 = blockIdx.x * 64;
    const int t = threadIdx.x;
    if (t < 64)        su[t]      = __expf(0.5f * Wu[n0 + t]);
    else if (t < 128)  sv[t - 64] = __expf(0.5f * Wv[m0 + t - 64]);
    __syncthreads();
    // phase 1: coalesced float4 reads of Wm/eps rows, bf16 into LDS tile
    for (int c = t; c < 1024; c += 256) {            // 64 rows x 16 float4-chunks
        const int row = c >> 4, c4 = c & 15;
        const long g = (long)(n0 + row) * M + m0 + c4 * 4;
        float4 wm = *(const float4*)&Wm[g];
        float4 ep = *(const float4*)&eps[g];
        const float s = su[row];
        short4 o;
        o.x = f2bf(wm.x + s * ep.x * sv[c4 * 4 + 0]);
        o.y = f2bf(wm.y + s * ep.y * sv[c4 * 4 + 1]);
        o.z = f2bf(wm.z + s * ep.z * sv[c4 * 4 + 2]);
        o.w = f2bf(wm.w + s * ep.w * sv[c4 * 4 + 3]);
        *(short4*)&tile[row][c4 * 4] = o;
    }
    __syncthreads();
    // phase 2: write transposed, 16B coalesced along n
    for (int c = t; c < 512; c += 256) {             // 64 out-rows x 8 short8-chunks
        const int mm = c >> 3, nn8 = (c & 7) * 8;
        bf16x8 o;
        #pragma unroll
        for (int j = 0; j < 8; ++j) o[j] = tile[nn8 + j][mm];
        *(bf16x8*)&Wt[(long)(m0 + mm) * N + n0 + nn8] = o;
    }
}

// ---------- GEMM: C[B][M] = A[B][K](bf16) @ Bt[M][K]^T (bf16), f32 out ----------
// m97 structure: 128x128 tile, BK=32, 4 waves (2x2 of 64x64), global_load_lds x16B,
// 2 barriers / K-step. Known-good ~900 TF shape on gfx950.
__global__ __launch_bounds__(256) void gemm_bt(const short* __restrict__ A,
                                               const short* __restrict__ Bt,
                                               float* __restrict__ C,
                                               int K, int M) {
    __shared__ __align__(16) short lA[128 * 32];
    __shared__ __align__(16) short lB[128 * 32];
    const int tid  = threadIdx.x;
    const int wid  = tid >> 6;
    const int lane = tid & 63;
    const int brow = blockIdx.y * 128;
    const int bcol = blockIdx.x * 128;
    const int wr = (wid >> 1) * 64;   // wave row offset in tile
    const int wc = (wid & 1) * 64;    // wave col offset in tile

    f32x4 acc[4][4];
    #pragma unroll
    for (int m = 0; m < 4; ++m)
        #pragma unroll
        for (int n = 0; n < 4; ++n) acc[m][n] = {0.f, 0.f, 0.f, 0.f};

    // staging: tile = 512 x 16B chunks; chunk c -> row c>>2, k-elems (c&3)*8
    const int c0 = wid * 64 + lane;
    const int c1 = c0 + 256;
    const short* gA0 = A  + (long)(brow + (c0 >> 2)) * K + (c0 & 3) * 8;
    const short* gA1 = A  + (long)(brow + (c1 >> 2)) * K + (c1 & 3) * 8;
    const short* gB0 = Bt + (long)(bcol + (c0 >> 2)) * K + (c0 & 3) * 8;
    const short* gB1 = Bt + (long)(bcol + (c1 >> 2)) * K + (c1 & 3) * 8;
    char* lA0 = (char*)lA + wid * 1024;          // wave-uniform LDS bases
    char* lA1 = (char*)lA + wid * 1024 + 4096;
    char* lB0 = (char*)lB + wid * 1024;
    char* lB1 = (char*)lB + wid * 1024 + 4096;

    const int nk = K >> 5;
    for (int kt = 0; kt < nk; ++kt) {
        const int k0 = kt << 5;
        gload16(gA0 + k0, lA0);
        gload16(gA1 + k0, lA1);
        gload16(gB0 + k0, lB0);
        gload16(gB1 + k0, lB1);
        __syncthreads();                          // compiler emits vmcnt(0) drain
        bf16x8 af[4], bfr[4];
        #pragma unroll
        for (int m = 0; m < 4; ++m)
            af[m] = *(const bf16x8*)&lA[(wr + m * 16 + (lane & 15)) * 32 + (lane >> 4) * 8];
        #pragma unroll
        for (int n = 0; n < 4; ++n)
            bfr[n] = *(const bf16x8*)&lB[(wc + n * 16 + (lane & 15)) * 32 + (lane >> 4) * 8];
        #pragma unroll
        for (int m = 0; m < 4; ++m)
            #pragma unroll
            for (int n = 0; n < 4; ++n)
                acc[m][n] = __builtin_amdgcn_mfma_f32_16x16x32_bf16(af[m], bfr[n], acc[m][n], 0, 0, 0);
        __syncthreads();
    }

    // epilogue: C/D map col=lane&15, row=(lane>>4)*4+j  [m89-verified]
    const int cr = (lane >> 4) * 4;
    const int cc = lane & 15;
    #pragma unroll
    for (int m = 0; m < 4; ++m)
        #pragma unroll
        for (int n = 0; n < 4; ++n) {
            const long base = (long)(brow + wr + m * 16 + cr) * M + (bcol + wc + n * 16 + cc);
            #pragma unroll
            for (int j = 0; j < 4; ++j)
                C[base + (long)j * M] = acc[m][n][j];
        }
}

extern "C" void kernel_launch(void* const* d_in, const int* in_sizes, int n_in,
                              void* d_out, int out_size, void* d_ws, size_t ws_size,
                              hipStream_t stream) {
    const float* x   = (const float*)d_in[0];
    const float* Wm  = (const float*)d_in[1];
    const float* Wu  = (const float*)d_in[2];
    const float* Wv  = (const float*)d_in[3];
    const float* eps = (const float*)d_in[4];
    float* out = (float*)d_out;

    const int N = in_sizes[2];              // 4096 (input size)
    const int M = in_sizes[3];              // 4096 (output size)
    const int B = in_sizes[0] / N;          // 8192 (tokens)

    short* xb = (short*)d_ws;                                  // [B][N] bf16, 64 MB
    short* wt = (short*)((char*)d_ws + (size_t)B * N * 2);     // [M][N] bf16, 32 MB

    cvt_x<<<2048, 256, 0, stream>>>(x, xb, (long)B * N);
    build_wt<<<dim3(M / 64, N / 64), 256, 0, stream>>>(Wm, eps, Wu, Wv, wt, N, M);
    gemm_bt<<<dim3(M / 128, B / 128), 256, 0, stream>>>(xb, wt, out, N, M);
}

// Round 2
// 557.960 us; speedup vs baseline: 1.2251x; 1.2251x over previous
//
#include <hip/hip_runtime.h>
#include <hip/hip_bf16.h>

typedef short bf16x8 __attribute__((ext_vector_type(8)));
typedef short short8 __attribute__((ext_vector_type(8)));
typedef float f32x4  __attribute__((ext_vector_type(4)));

__device__ __forceinline__ short f2bf(float f) {
    union { float f; unsigned u; } a; a.f = f;
    unsigned r = a.u + 0x7fffu + ((a.u >> 16) & 1u);
    return (short)(r >> 16);
}

__device__ __forceinline__ void gload16(const void* g, void* l) {
    __builtin_amdgcn_global_load_lds(
        (const __attribute__((address_space(1))) unsigned int*)g,
        (__attribute__((address_space(3))) unsigned int*)l,
        16, 0, 0);
}

// ---------- prep 1: x f32 -> bf16 (short8) ----------
__global__ __launch_bounds__(256) void cvt_x(const float* __restrict__ x,
                                             short* __restrict__ xb, long n) {
    const long t = (long)blockIdx.x * blockDim.x + threadIdx.x;
    const long stride = (long)gridDim.x * blockDim.x;
    for (long i = t * 8; i < n; i += stride * 8) {
        float4 v0 = *(const float4*)&x[i];
        float4 v1 = *(const float4*)&x[i + 4];
        short8 o;
        o[0] = f2bf(v0.x); o[1] = f2bf(v0.y); o[2] = f2bf(v0.z); o[3] = f2bf(v0.w);
        o[4] = f2bf(v1.x); o[5] = f2bf(v1.y); o[6] = f2bf(v1.z); o[7] = f2bf(v1.w);
        *(short8*)&xb[i] = o;
    }
}

// ---------- prep 2: W = Wm + exp(.5u)*eps*exp(.5v), bf16, transposed -> Wt[M][N] ----------
__global__ __launch_bounds__(256) void build_wt(const float* __restrict__ Wm,
                                                const float* __restrict__ eps,
                                                const float* __restrict__ Wu,
                                                const float* __restrict__ Wv,
                                                short* __restrict__ Wt,
                                                int N, int M) {
    __shared__ __align__(16) short tile[64][68];
    __shared__ float su[64], sv[64];
    const int n0 = blockIdx.y * 64, m0 = blockIdx.x * 64;
    const int t = threadIdx.x;
    if (t < 64)        su[t]      = __expf(0.5f * Wu[n0 + t]);
    else if (t < 128)  sv[t - 64] = __expf(0.5f * Wv[m0 + t - 64]);
    __syncthreads();
    for (int c = t; c < 1024; c += 256) {
        const int row = c >> 4, c4 = c & 15;
        const long g = (long)(n0 + row) * M + m0 + c4 * 4;
        float4 wm = *(const float4*)&Wm[g];
        float4 ep = *(const float4*)&eps[g];
        const float s = su[row];
        short4 o;
        o.x = f2bf(wm.x + s * ep.x * sv[c4 * 4 + 0]);
        o.y = f2bf(wm.y + s * ep.y * sv[c4 * 4 + 1]);
        o.z = f2bf(wm.z + s * ep.z * sv[c4 * 4 + 2]);
        o.w = f2bf(wm.w + s * ep.w * sv[c4 * 4 + 3]);
        *(short4*)&tile[row][c4 * 4] = o;
    }
    __syncthreads();
    for (int c = t; c < 512; c += 256) {
        const int mm = c >> 3, nn8 = (c & 7) * 8;
        bf16x8 o;
        #pragma unroll
        for (int j = 0; j < 8; ++j) o[j] = tile[nn8 + j][mm];
        *(bf16x8*)&Wt[(long)(m0 + mm) * N + n0 + nn8] = o;
    }
}

// ---------- GEMM: 256x256 tile, BK=64, 8 waves, 8-phase counted-vmcnt schedule ----------
// C[8192][4096] = A[8192][4096] @ Wt[4096][4096]^T, all dims hardcoded.
// LDS map (bytes): A: buf*32768 + half*16384 + row*128 + slot*16   (slot = k16 ^ (row&7))
//                  B: 65536 + same.  Total 128 KiB.
#define KDIM 4096

template<int BUF, int MH, int NH>
__device__ __forceinline__ void phase_loads(const char* sm, int aoff, int boff,
                                            int c0, int c1,
                                            bf16x8 (&a)[4][2], bf16x8 (&b)[2][2]) {
    const char* pa = sm + BUF * 32768 + MH * 16384 + aoff;
    const char* pb = sm + 65536 + BUF * 32768 + NH * 16384 + boff;
    #pragma unroll
    for (int mf = 0; mf < 4; ++mf) {
        a[mf][0] = *(const bf16x8*)(pa + mf * 2048 + c0);
        a[mf][1] = *(const bf16x8*)(pa + mf * 2048 + c1);
    }
    #pragma unroll
    for (int nf = 0; nf < 2; ++nf) {
        b[nf][0] = *(const bf16x8*)(pb + nf * 2048 + c0);
        b[nf][1] = *(const bf16x8*)(pb + nf * 2048 + c1);
    }
}

template<int MH, int NH>
__device__ __forceinline__ void phase_mfma(const bf16x8 (&a)[4][2], const bf16x8 (&b)[2][2],
                                           f32x4 (&acc)[8][4]) {
    #pragma unroll
    for (int mf = 0; mf < 4; ++mf)
        #pragma unroll
        for (int nf = 0; nf < 2; ++nf)
            #pragma unroll
            for (int ks = 0; ks < 2; ++ks)
                acc[MH * 4 + mf][NH * 2 + nf] = __builtin_amdgcn_mfma_f32_16x16x32_bf16(
                    a[mf][ks], b[nf][ks], acc[MH * 4 + mf][NH * 2 + nf], 0, 0, 0);
}

__device__ __forceinline__ void stage2(const short* g, char* l) {
    gload16(g, l);
    gload16(g + 8 * KDIM, l + 1024);   // second 64-chunk group: rows +8, same swizzled k
}

__global__ __launch_bounds__(512, 2) void gemm256(const short* __restrict__ A,
                                                  const short* __restrict__ Bt,
                                                  float* __restrict__ C) {
    __shared__ __align__(16) char smem[131072];
    const char* smc = smem;

    const int tid = threadIdx.x;
    const int wid = tid >> 6, lane = tid & 63;
    const int wm = wid >> 2, wn = wid & 3;
    const int l15 = lane & 15, l4 = lane >> 4;

    // XCD-chunked block swizzle (512 blocks, 512%8==0)
    const int bsw = (blockIdx.x & 7) * 64 + (blockIdx.x >> 3);
    const int bx = bsw & 15, by = bsw >> 4;
    const int brow = by * 256, bcol = bx * 256;

    // ds_read addressing
    const int s7 = l15 & 7;
    const int c0 = ((l4) ^ s7) * 16;        // ks=0 chunk byte
    const int c1 = ((l4 + 4) ^ s7) * 16;    // ks=1
    const int aoff = (wm * 64 + l15) * 128;
    const int boff = (wn * 32 + l15) * 128;

    // staging addressing: chunk p = wid*128 + lane (+64 for 2nd instr)
    const int p0 = wid * 128 + lane;
    const int srow = p0 >> 3;                    // 0..127 row within half
    const int sk = (p0 & 7) ^ (srow & 7);        // swizzled source chunk
    const short* gA = A  + (long)(brow + srow) * KDIM + sk * 8;
    const short* gB = Bt + (long)(bcol + srow) * KDIM + sk * 8;
    char* smw = smem + wid * 2048;               // wave-uniform LDS base

#define STAGE_A(BUF, H, T) stage2(gA + (H) * (128 * KDIM) + (T) * 64, smw + (BUF) * 32768 + (H) * 16384)
#define STAGE_B(BUF, H, T) stage2(gB + (H) * (128 * KDIM) + (T) * 64, smw + 65536 + (BUF) * 32768 + (H) * 16384)

    f32x4 acc[8][4];
    #pragma unroll
    for (int i = 0; i < 8; ++i)
        #pragma unroll
        for (int j = 0; j < 4; ++j) acc[i][j] = {0.f, 0.f, 0.f, 0.f};

    // prologue: tile0 full (A0,B0,B1,A1 of buf0) + tile1 first halves (A0,B0 of buf1)
    STAGE_A(0, 0, 0);
    STAGE_B(0, 0, 0);
    STAGE_B(0, 1, 0);
    STAGE_A(0, 1, 0);
    STAGE_A(1, 0, 1);
    STAGE_B(1, 0, 1);
    asm volatile("s_waitcnt vmcnt(4)" ::: "memory");  // tile0 landed; 2 halves in flight
    __builtin_amdgcn_s_barrier();

#define PHASE(BUF, MH, NH, STAGE_STMT, VM_STMT) {                          \
        bf16x8 afr[4][2], bfr[2][2];                                       \
        phase_loads<BUF, MH, NH>(smc, aoff, boff, c0, c1, afr, bfr);       \
        STAGE_STMT;                                                        \
        VM_STMT;                                                           \
        __builtin_amdgcn_s_barrier();                                      \
        asm volatile("s_waitcnt lgkmcnt(0)");                              \
        __builtin_amdgcn_s_setprio(1);                                     \
        phase_mfma<MH, NH>(afr, bfr, acc);                                 \
        __builtin_amdgcn_s_setprio(0);                                     \
        __builtin_amdgcn_s_barrier();                                      \
    }
#define VM4 asm volatile("s_waitcnt vmcnt(4)" ::: "memory")

    // 64 K-tiles, 32 iterations of 2 tiles / 8 phases.
    // Stage schedule (region freed -> slot):  ph1:Bb1h1(T+1) ph2:Ab1h1(T+1)
    // ph3:Ab0h0(T+2) ph4:Bb0h0(T+2)+VM ph5:Bb0h1(T+2) ph6:Ab0h1(T+2)
    // ph7:Ab1h0(T+3) ph8:Bb1h0(T+3)+VM.  Wrapped tiles = dead writes into freed regions.
    for (int it = 0; it < 32; ++it) {
        const int T = 2 * it;
        const int t1 = T + 1;            // never wraps (<= 63)
        const int t2 = (T + 2) & 63;
        const int t3 = (T + 3) & 63;
        PHASE(0, 0, 0, STAGE_B(1, 1, t1), );
        PHASE(0, 0, 1, STAGE_A(1, 1, t1), );
        PHASE(0, 1, 0, STAGE_A(0, 0, t2), );
        PHASE(0, 1, 1, STAGE_B(0, 0, t2), VM4);
        PHASE(1, 0, 0, STAGE_B(0, 1, t2), );
        PHASE(1, 0, 1, STAGE_A(0, 1, t2), );
        PHASE(1, 1, 0, STAGE_A(1, 0, t3), );
        PHASE(1, 1, 1, STAGE_B(1, 0, t3), VM4);
    }

    // epilogue: D map col=lane&15, row=(lane>>4)*4+j
    const int cr = l4 * 4;
    #pragma unroll
    for (int mh = 0; mh < 2; ++mh)
        #pragma unroll
        for (int mf = 0; mf < 4; ++mf) {
            const long row = brow + mh * 128 + wm * 64 + mf * 16 + cr;
            #pragma unroll
            for (int nh = 0; nh < 2; ++nh)
                #pragma unroll
                for (int nf = 0; nf < 2; ++nf) {
                    const long col = bcol + nh * 128 + wn * 32 + nf * 16 + l15;
                    const f32x4 v = acc[mh * 4 + mf][nh * 2 + nf];
                    float* p = C + row * 4096 + col;
                    p[0]        = v[0];
                    p[4096]     = v[1];
                    p[2 * 4096] = v[2];
                    p[3 * 4096] = v[3];
                }
        }
#undef PHASE
#undef VM4
#undef STAGE_A
#undef STAGE_B
}

extern "C" void kernel_launch(void* const* d_in, const int* in_sizes, int n_in,
                              void* d_out, int out_size, void* d_ws, size_t ws_size,
                              hipStream_t stream) {
    const float* x   = (const float*)d_in[0];
    const float* Wm  = (const float*)d_in[1];
    const float* Wu  = (const float*)d_in[2];
    const float* Wv  = (const float*)d_in[3];
    const float* eps = (const float*)d_in[4];
    float* out = (float*)d_out;

    const int N = in_sizes[2];              // 4096
    const int M = in_sizes[3];              // 4096
    const int B = in_sizes[0] / N;          // 8192

    short* xb = (short*)d_ws;                                  // [B][N] bf16
    short* wt = (short*)((char*)d_ws + (size_t)B * N * 2);     // [M][N] bf16

    cvt_x<<<2048, 256, 0, stream>>>(x, xb, (long)B * N);
    build_wt<<<dim3(M / 64, N / 64), 256, 0, stream>>>(Wm, eps, Wu, Wv, wt, N, M);
    gemm256<<<dim3((B / 256) * (M / 256)), 512, 0, stream>>>(xb, wt, out);
}

// Round 4
// 537.323 us; speedup vs baseline: 1.2721x; 1.0384x over previous
//
#include <hip/hip_runtime.h>
#include <hip/hip_bf16.h>

typedef short bf16x8 __attribute__((ext_vector_type(8)));
typedef short short8 __attribute__((ext_vector_type(8)));
typedef float f32x4  __attribute__((ext_vector_type(4)));

__device__ __forceinline__ short f2bf(float f) {
    union { float f; unsigned u; } a; a.f = f;
    unsigned r = a.u + 0x7fffu + ((a.u >> 16) & 1u);
    return (short)(r >> 16);
}

__device__ __forceinline__ void gload16(const void* g, void* l) {
    __builtin_amdgcn_global_load_lds(
        (const __attribute__((address_space(1))) unsigned int*)g,
        (__attribute__((address_space(3))) unsigned int*)l,
        16, 0, 0);
}

// ---------- prep 1: x f32 -> bf16 (short8) ----------
__global__ __launch_bounds__(256) void cvt_x(const float* __restrict__ x,
                                             short* __restrict__ xb, long n) {
    const long t = (long)blockIdx.x * blockDim.x + threadIdx.x;
    const long stride = (long)gridDim.x * blockDim.x;
    for (long i = t * 8; i < n; i += stride * 8) {
        float4 v0 = *(const float4*)&x[i];
        float4 v1 = *(const float4*)&x[i + 4];
        short8 o;
        o[0] = f2bf(v0.x); o[1] = f2bf(v0.y); o[2] = f2bf(v0.z); o[3] = f2bf(v0.w);
        o[4] = f2bf(v1.x); o[5] = f2bf(v1.y); o[6] = f2bf(v1.z); o[7] = f2bf(v1.w);
        *(short8*)&xb[i] = o;
    }
}

// ---------- prep 2: W = Wm + exp(.5u)*eps*exp(.5v), bf16, transposed -> Wt[M][N] ----------
__global__ __launch_bounds__(256) void build_wt(const float* __restrict__ Wm,
                                                const float* __restrict__ eps,
                                                const float* __restrict__ Wu,
                                                const float* __restrict__ Wv,
                                                short* __restrict__ Wt,
                                                int N, int M) {
    __shared__ __align__(16) short tile[64][68];
    __shared__ float su[64], sv[64];
    const int n0 = blockIdx.y * 64, m0 = blockIdx.x * 64;
    const int t = threadIdx.x;
    if (t < 64)        su[t]      = __expf(0.5f * Wu[n0 + t]);
    else if (t < 128)  sv[t - 64] = __expf(0.5f * Wv[m0 + t - 64]);
    __syncthreads();
    for (int c = t; c < 1024; c += 256) {
        const int row = c >> 4, c4 = c & 15;
        const long g = (long)(n0 + row) * M + m0 + c4 * 4;
        float4 wm = *(const float4*)&Wm[g];
        float4 ep = *(const float4*)&eps[g];
        const float s = su[row];
        short4 o;
        o.x = f2bf(wm.x + s * ep.x * sv[c4 * 4 + 0]);
        o.y = f2bf(wm.y + s * ep.y * sv[c4 * 4 + 1]);
        o.z = f2bf(wm.z + s * ep.z * sv[c4 * 4 + 2]);
        o.w = f2bf(wm.w + s * ep.w * sv[c4 * 4 + 3]);
        *(short4*)&tile[row][c4 * 4] = o;
    }
    __syncthreads();
    for (int c = t; c < 512; c += 256) {
        const int mm = c >> 3, nn8 = (c & 7) * 8;
        bf16x8 o;
        #pragma unroll
        for (int j = 0; j < 8; ++j) o[j] = tile[nn8 + j][mm];
        *(bf16x8*)&Wt[(long)(m0 + mm) * N + n0 + nn8] = o;
    }
}

// ---------- GEMM: 256x256 tile, BK=64, 8 waves, 8-phase counted-vmcnt schedule ----------
// Reg-cached fragments: each A-half / B-quarter ds_read ONCE per K-tile
// (phase order (0,0)->(0,1)->(1,1)->(1,0); reads 12/4/8/0 per phase).
// LDS map (bytes): A: buf*32768 + half*16384 + row*128 + slot*16   (slot = k16 ^ (row&7))
//                  B: 65536 + same.  Total 128 KiB.
#define KDIM 4096

template<int BUF, int MH>
__device__ __forceinline__ void load_a(const char* sm, int aoff, int c0, int c1,
                                       bf16x8 (&a)[4][2]) {
    const char* pa = sm + BUF * 32768 + MH * 16384 + aoff;
    #pragma unroll
    for (int mf = 0; mf < 4; ++mf) {
        a[mf][0] = *(const bf16x8*)(pa + mf * 2048 + c0);
        a[mf][1] = *(const bf16x8*)(pa + mf * 2048 + c1);
    }
}

template<int BUF, int NH>
__device__ __forceinline__ void load_b(const char* sm, int boff, int c0, int c1,
                                       bf16x8 (&b)[2][2]) {
    const char* pb = sm + 65536 + BUF * 32768 + NH * 16384 + boff;
    #pragma unroll
    for (int nf = 0; nf < 2; ++nf) {
        b[nf][0] = *(const bf16x8*)(pb + nf * 2048 + c0);
        b[nf][1] = *(const bf16x8*)(pb + nf * 2048 + c1);
    }
}

template<int MH, int NH>
__device__ __forceinline__ void do_mfma(const bf16x8 (&a)[4][2], const bf16x8 (&b)[2][2],
                                        f32x4 (&acc)[8][4]) {
    #pragma unroll
    for (int mf = 0; mf < 4; ++mf)
        #pragma unroll
        for (int nf = 0; nf < 2; ++nf)
            #pragma unroll
            for (int ks = 0; ks < 2; ++ks)
                acc[MH * 4 + mf][NH * 2 + nf] = __builtin_amdgcn_mfma_f32_16x16x32_bf16(
                    a[mf][ks], b[nf][ks], acc[MH * 4 + mf][NH * 2 + nf], 0, 0, 0);
}

__device__ __forceinline__ void stage2(const short* g, char* l) {
    gload16(g, l);
    gload16(g + 8 * KDIM, l + 1024);
}

__global__ __launch_bounds__(512, 2) void gemm256(const short* __restrict__ A,
                                                  const short* __restrict__ Bt,
                                                  float* __restrict__ C) {
    __shared__ __align__(16) char smem[131072];
    const char* smc = smem;

    const int tid = threadIdx.x;
    const int wid = tid >> 6, lane = tid & 63;
    const int wm = wid >> 2, wn = wid & 3;
    const int l15 = lane & 15, l4 = lane >> 4;

    // XCD-chunked block swizzle (512 blocks, 512%8==0)
    const int bsw = (blockIdx.x & 7) * 64 + (blockIdx.x >> 3);
    const int bx = bsw & 15, by = bsw >> 4;
    const int brow = by * 256, bcol = bx * 256;

    // ds_read addressing
    const int s7 = l15 & 7;
    const int c0 = ((l4) ^ s7) * 16;
    const int c1 = ((l4 + 4) ^ s7) * 16;
    const int aoff = (wm * 64 + l15) * 128;
    const int boff = (wn * 32 + l15) * 128;

    // staging addressing
    const int p0 = wid * 128 + lane;
    const int srow = p0 >> 3;
    const int sk = (p0 & 7) ^ (srow & 7);
    const short* gA = A  + (long)(brow + srow) * KDIM + sk * 8;
    const short* gB = Bt + (long)(bcol + srow) * KDIM + sk * 8;
    char* smw = smem + wid * 2048;

#define STAGE_A(BUF, H, T) stage2(gA + (H) * (128 * KDIM) + (T) * 64, smw + (BUF) * 32768 + (H) * 16384)
#define STAGE_B(BUF, H, T) stage2(gB + (H) * (128 * KDIM) + (T) * 64, smw + 65536 + (BUF) * 32768 + (H) * 16384)
#define BAR   __builtin_amdgcn_s_barrier()
#define LGKM0 asm volatile("s_waitcnt lgkmcnt(0)")
#define LGKM8 asm volatile("s_waitcnt lgkmcnt(8)")
#define VM4   asm volatile("s_waitcnt vmcnt(4)" ::: "memory")
#define PRIO1 __builtin_amdgcn_s_setprio(1)
#define PRIO0 __builtin_amdgcn_s_setprio(0)

    f32x4 acc[8][4];
    #pragma unroll
    for (int i = 0; i < 8; ++i)
        #pragma unroll
        for (int j = 0; j < 4; ++j) acc[i][j] = {0.f, 0.f, 0.f, 0.f};

    // prologue: tile0 full (buf0) + tile1 first halves (buf1)
    STAGE_A(0, 0, 0);
    STAGE_B(0, 0, 0);
    STAGE_B(0, 1, 0);
    STAGE_A(0, 1, 0);
    STAGE_A(1, 0, 1);
    STAGE_B(1, 0, 1);
    asm volatile("s_waitcnt vmcnt(4)" ::: "memory");
    BAR;

    bf16x8 Afr[4][2], B0fr[2][2], B1fr[2][2];

    // 64 K-tiles, 32 iterations x 2 tiles / 8 phases.
    // Stage slots: ph1:Bb1h1(T+1) ph2:Ab1h1(T+1) ph3:Ab0h0(T+2) ph4:Bb0h0(T+2)+VM
    //              ph5:Bb0h1(T+2) ph6:Ab0h1(T+2) ph7:Ab1h0(T+3) ph8:Bb1h0(T+3)+VM
    for (int it = 0; it < 32; ++it) {
        const int T = 2 * it;
        const int t1 = T + 1;
        const int t2 = (T + 2) & 63;
        const int t3 = (T + 3) & 63;

        // ---- K-tile T (buf0) ----
        // ph1 (0,0): read A0 + B0
        load_a<0, 0>(smc, aoff, c0, c1, Afr);
        load_b<0, 0>(smc, boff, c0, c1, B0fr);
        STAGE_B(1, 1, t1);
        LGKM8; BAR; LGKM0;
        PRIO1; do_mfma<0, 0>(Afr, B0fr, acc); PRIO0;
        BAR;
        // ph2 (0,1): read B1, reuse A0
        load_b<0, 1>(smc, boff, c0, c1, B1fr);
        STAGE_A(1, 1, t1);
        BAR; LGKM0;
        PRIO1; do_mfma<0, 1>(Afr, B1fr, acc); PRIO0;
        BAR;
        // ph3 (1,1): read A1, reuse B1
        load_a<0, 1>(smc, aoff, c0, c1, Afr);
        STAGE_A(0, 0, t2);
        BAR; LGKM0;
        PRIO1; do_mfma<1, 1>(Afr, B1fr, acc); PRIO0;
        BAR;
        // ph4 (1,0): no reads, reuse A1 + B0
        STAGE_B(0, 0, t2);
        VM4; BAR;
        PRIO1; do_mfma<1, 0>(Afr, B0fr, acc); PRIO0;
        BAR;

        // ---- K-tile T+1 (buf1) ----
        // ph5 (0,0)
        load_a<1, 0>(smc, aoff, c0, c1, Afr);
        load_b<1, 0>(smc, boff, c0, c1, B0fr);
        STAGE_B(0, 1, t2);
        LGKM8; BAR; LGKM0;
        PRIO1; do_mfma<0, 0>(Afr, B0fr, acc); PRIO0;
        BAR;
        // ph6 (0,1)
        load_b<1, 1>(smc, boff, c0, c1, B1fr);
        STAGE_A(0, 1, t2);
        BAR; LGKM0;
        PRIO1; do_mfma<0, 1>(Afr, B1fr, acc); PRIO0;
        BAR;
        // ph7 (1,1)
        load_a<1, 1>(smc, aoff, c0, c1, Afr);
        STAGE_A(1, 0, t3);
        BAR; LGKM0;
        PRIO1; do_mfma<1, 1>(Afr, B1fr, acc); PRIO0;
        BAR;
        // ph8 (1,0)
        STAGE_B(1, 0, t3);
        VM4; BAR;
        PRIO1; do_mfma<1, 0>(Afr, B0fr, acc); PRIO0;
        BAR;
    }

    // epilogue: D map col=lane&15, row=(lane>>4)*4+j
    const int cr = l4 * 4;
    #pragma unroll
    for (int mh = 0; mh < 2; ++mh)
        #pragma unroll
        for (int mf = 0; mf < 4; ++mf) {
            const long row = brow + mh * 128 + wm * 64 + mf * 16 + cr;
            #pragma unroll
            for (int nh = 0; nh < 2; ++nh)
                #pragma unroll
                for (int nf = 0; nf < 2; ++nf) {
                    const long col = bcol + nh * 128 + wn * 32 + nf * 16 + l15;
                    const f32x4 v = acc[mh * 4 + mf][nh * 2 + nf];
                    float* p = C + row * 4096 + col;
                    p[0]        = v[0];
                    p[4096]     = v[1];
                    p[2 * 4096] = v[2];
                    p[3 * 4096] = v[3];
                }
        }
#undef STAGE_A
#undef STAGE_B
#undef BAR
#undef LGKM0
#undef LGKM8
#undef VM4
#undef PRIO1
#undef PRIO0
}

extern "C" void kernel_launch(void* const* d_in, const int* in_sizes, int n_in,
                              void* d_out, int out_size, void* d_ws, size_t ws_size,
                              hipStream_t stream) {
    const float* x   = (const float*)d_in[0];
    const float* Wm  = (const float*)d_in[1];
    const float* Wu  = (const float*)d_in[2];
    const float* Wv  = (const float*)d_in[3];
    const float* eps = (const float*)d_in[4];
    float* out = (float*)d_out;

    const int N = in_sizes[2];              // 4096
    const int M = in_sizes[3];              // 4096
    const int B = in_sizes[0] / N;          // 8192

    short* xb = (short*)d_ws;                                  // [B][N] bf16
    short* wt = (short*)((char*)d_ws + (size_t)B * N * 2);     // [M][N] bf16

    cvt_x<<<2048, 256, 0, stream>>>(x, xb, (long)B * N);
    build_wt<<<dim3(M / 64, N / 64), 256, 0, stream>>>(Wm, eps, Wu, Wv, wt, N, M);
    gemm256<<<dim3((B / 256) * (M / 256)), 512, 0, stream>>>(xb, wt, out);
}

// Round 7
// 522.779 us; speedup vs baseline: 1.3075x; 1.0278x over previous
//
#include <hip/hip_runtime.h>
#include <hip/hip_bf16.h>

typedef short bf16x8 __attribute__((ext_vector_type(8)));
typedef short short8 __attribute__((ext_vector_type(8)));
typedef float f32x4  __attribute__((ext_vector_type(4)));

__device__ __forceinline__ short f2bf(float f) {
    union { float f; unsigned u; } a; a.f = f;
    unsigned r = a.u + 0x7fffu + ((a.u >> 16) & 1u);
    return (short)(r >> 16);
}

__device__ __forceinline__ void gload16(const void* g, void* l) {
    __builtin_amdgcn_global_load_lds(
        (const __attribute__((address_space(1))) unsigned int*)g,
        (__attribute__((address_space(3))) unsigned int*)l,
        16, 0, 0);
}

// ---------- prep 1: x f32 -> bf16 (short8) ----------
__global__ __launch_bounds__(256) void cvt_x(const float* __restrict__ x,
                                             short* __restrict__ xb, long n) {
    const long t = (long)blockIdx.x * blockDim.x + threadIdx.x;
    const long stride = (long)gridDim.x * blockDim.x;
    for (long i = t * 8; i < n; i += stride * 8) {
        float4 v0 = *(const float4*)&x[i];
        float4 v1 = *(const float4*)&x[i + 4];
        short8 o;
        o[0] = f2bf(v0.x); o[1] = f2bf(v0.y); o[2] = f2bf(v0.z); o[3] = f2bf(v0.w);
        o[4] = f2bf(v1.x); o[5] = f2bf(v1.y); o[6] = f2bf(v1.z); o[7] = f2bf(v1.w);
        *(short8*)&xb[i] = o;
    }
}

// ---------- prep 2: W = Wm + exp(.5u)*eps*exp(.5v), bf16, transposed -> Wt[M][N] ----------
__global__ __launch_bounds__(256) void build_wt(const float* __restrict__ Wm,
                                                const float* __restrict__ eps,
                                                const float* __restrict__ Wu,
                                                const float* __restrict__ Wv,
                                                short* __restrict__ Wt,
                                                int N, int M) {
    __shared__ __align__(16) short tile[64][68];
    __shared__ float su[64], sv[64];
    const int n0 = blockIdx.y * 64, m0 = blockIdx.x * 64;
    const int t = threadIdx.x;
    if (t < 64)        su[t]      = __expf(0.5f * Wu[n0 + t]);
    else if (t < 128)  sv[t - 64] = __expf(0.5f * Wv[m0 + t - 64]);
    __syncthreads();
    for (int c = t; c < 1024; c += 256) {
        const int row = c >> 4, c4 = c & 15;
        const long g = (long)(n0 + row) * M + m0 + c4 * 4;
        float4 wm = *(const float4*)&Wm[g];
        float4 ep = *(const float4*)&eps[g];
        const float s = su[row];
        short4 o;
        o.x = f2bf(wm.x + s * ep.x * sv[c4 * 4 + 0]);
        o.y = f2bf(wm.y + s * ep.y * sv[c4 * 4 + 1]);
        o.z = f2bf(wm.z + s * ep.z * sv[c4 * 4 + 2]);
        o.w = f2bf(wm.w + s * ep.w * sv[c4 * 4 + 3]);
        *(short4*)&tile[row][c4 * 4] = o;
    }
    __syncthreads();
    for (int c = t; c < 512; c += 256) {
        const int mm = c >> 3, nn8 = (c & 7) * 8;
        bf16x8 o;
        #pragma unroll
        for (int j = 0; j < 8; ++j) o[j] = tile[nn8 + j][mm];
        *(bf16x8*)&Wt[(long)(m0 + mm) * N + n0 + nn8] = o;
    }
}

// ---------- GEMM: 256x256 tile, BK=64, 8 waves, 8-phase counted-vmcnt schedule ----------
// Balanced reg-cached reads, 8/4/8/4 per phase (B-h0 pulled one phase early
// into a second B0 register set):
//   read slots:  ph1:A-b0h0(T) ph2:B-b0h1(T) ph3:A-b0h1(T) ph4:B-b1h0(T+1)
//                ph5:A-b1h0    ph6:B-b1h1    ph7:A-b1h1    ph8:B-b0h0(T+2)
//   MFMA slots:  ph1:(0,0)T ph2:(0,1)T ph3:(1,1)T ph4:(1,0)T  then same for T+1
//   stage slots: ph1:Bb0h0(T+2) ph2:Ab0h0 ph3:Bb0h1 ph4:Ab0h1(+VM4)
//                ph5:Bb1h0(T+3) ph6:Ab1h0 ph7:Bb1h1 ph8:Ab1h1(+VM4)
// Every read covered by prior VM4+barrier; every stage >=1 barrier after the
// old region's last (drained) read.  LDS map unchanged (slot = k16 ^ (row&7)).
#define KDIM 4096

template<int BUF, int MH>
__device__ __forceinline__ void load_a(const char* sm, int aoff, int c0, int c1,
                                       bf16x8 (&a)[4][2]) {
    const char* pa = sm + BUF * 32768 + MH * 16384 + aoff;
    #pragma unroll
    for (int mf = 0; mf < 4; ++mf) {
        a[mf][0] = *(const bf16x8*)(pa + mf * 2048 + c0);
        a[mf][1] = *(const bf16x8*)(pa + mf * 2048 + c1);
    }
}

template<int BUF, int NH>
__device__ __forceinline__ void load_b(const char* sm, int boff, int c0, int c1,
                                       bf16x8 (&b)[2][2]) {
    const char* pb = sm + 65536 + BUF * 32768 + NH * 16384 + boff;
    #pragma unroll
    for (int nf = 0; nf < 2; ++nf) {
        b[nf][0] = *(const bf16x8*)(pb + nf * 2048 + c0);
        b[nf][1] = *(const bf16x8*)(pb + nf * 2048 + c1);
    }
}

template<int MH, int NH>
__device__ __forceinline__ void do_mfma(const bf16x8 (&a)[4][2], const bf16x8 (&b)[2][2],
                                        f32x4 (&acc)[8][4]) {
    #pragma unroll
    for (int mf = 0; mf < 4; ++mf)
        #pragma unroll
        for (int nf = 0; nf < 2; ++nf)
            #pragma unroll
            for (int ks = 0; ks < 2; ++ks)
                acc[MH * 4 + mf][NH * 2 + nf] = __builtin_amdgcn_mfma_f32_16x16x32_bf16(
                    a[mf][ks], b[nf][ks], acc[MH * 4 + mf][NH * 2 + nf], 0, 0, 0);
}

__device__ __forceinline__ void stage2(const short* g, char* l) {
    gload16(g, l);
    gload16(g + 8 * KDIM, l + 1024);
}

__global__ __launch_bounds__(512, 2) void gemm256(const short* __restrict__ A,
                                                  const short* __restrict__ Bt,
                                                  float* __restrict__ C) {
    __shared__ __align__(16) char smem[131072];
    const char* smc = smem;

    const int tid = threadIdx.x;
    const int wid = tid >> 6, lane = tid & 63;
    const int wm = wid >> 2, wn = wid & 3;
    const int l15 = lane & 15, l4 = lane >> 4;

    // XCD-chunked block swizzle (512 blocks, 512%8==0)
    const int bsw = (blockIdx.x & 7) * 64 + (blockIdx.x >> 3);
    const int bx = bsw & 15, by = bsw >> 4;
    const int brow = by * 256, bcol = bx * 256;

    // ds_read addressing
    const int s7 = l15 & 7;
    const int c0 = ((l4) ^ s7) * 16;
    const int c1 = ((l4 + 4) ^ s7) * 16;
    const int aoff = (wm * 64 + l15) * 128;
    const int boff = (wn * 32 + l15) * 128;

    // staging addressing
    const int p0 = wid * 128 + lane;
    const int srow = p0 >> 3;
    const int sk = (p0 & 7) ^ (srow & 7);
    const short* gA = A  + (long)(brow + srow) * KDIM + sk * 8;
    const short* gB = Bt + (long)(bcol + srow) * KDIM + sk * 8;
    char* smw = smem + wid * 2048;

#define STAGE_A(BUF, H, T) stage2(gA + (H) * (128 * KDIM) + (T) * 64, smw + (BUF) * 32768 + (H) * 16384)
#define STAGE_B(BUF, H, T) stage2(gB + (H) * (128 * KDIM) + (T) * 64, smw + 65536 + (BUF) * 32768 + (H) * 16384)
#define BAR   __builtin_amdgcn_s_barrier()
#define LGKM0 asm volatile("s_waitcnt lgkmcnt(0)")
#define VM4   asm volatile("s_waitcnt vmcnt(4)" ::: "memory")
#define VM6   asm volatile("s_waitcnt vmcnt(6)" ::: "memory")
#define PRIO1 __builtin_amdgcn_s_setprio(1)
#define PRIO0 __builtin_amdgcn_s_setprio(0)

    f32x4 acc[8][4];
    #pragma unroll
    for (int i = 0; i < 8; ++i)
        #pragma unroll
        for (int j = 0; j < 4; ++j) acc[i][j] = {0.f, 0.f, 0.f, 0.f};

    // prologue: tile0 (buf0) full + tile1 (buf1) full, 16 gload_lds instrs.
    // Need first 10 (tile0 + Bb1h0) before ph1-4 reads -> vmcnt(6).
    STAGE_B(0, 0, 0);
    STAGE_A(0, 0, 0);
    STAGE_B(0, 1, 0);
    STAGE_A(0, 1, 0);
    STAGE_B(1, 0, 1);
    STAGE_A(1, 0, 1);
    STAGE_B(1, 1, 1);
    STAGE_A(1, 1, 1);
    VM6;
    BAR;

    bf16x8 Afr[4][2], B0a[2][2], B0b[2][2], B1fr[2][2];
    load_b<0, 0>(smc, boff, c0, c1, B0a);   // B0 of tile 0 (drained by ph1 LGKM0)

    for (int it = 0; it < 32; ++it) {
        const int T = 2 * it;
        const int t2 = (T + 2) & 63;
        const int t3 = (T + 3) & 63;

        // ---- K-tile T (buf0) ----
        // ph1 (0,0): read A-h0; B0 already in B0a
        load_a<0, 0>(smc, aoff, c0, c1, Afr);
        STAGE_B(0, 0, t2);
        BAR; LGKM0;
        PRIO1; do_mfma<0, 0>(Afr, B0a, acc); PRIO0;
        BAR;
        // ph2 (0,1): read B-h1
        load_b<0, 1>(smc, boff, c0, c1, B1fr);
        STAGE_A(0, 0, t2);
        BAR; LGKM0;
        PRIO1; do_mfma<0, 1>(Afr, B1fr, acc); PRIO0;
        BAR;
        // ph3 (1,1): read A-h1
        load_a<0, 1>(smc, aoff, c0, c1, Afr);
        STAGE_B(0, 1, t2);
        BAR; LGKM0;
        PRIO1; do_mfma<1, 1>(Afr, B1fr, acc); PRIO0;
        BAR;
        // ph4 (1,0): read-ahead B-h0 of tile T+1 (buf1)
        load_b<1, 0>(smc, boff, c0, c1, B0b);
        STAGE_A(0, 1, t2);
        VM4; BAR; LGKM0;
        PRIO1; do_mfma<1, 0>(Afr, B0a, acc); PRIO0;
        BAR;

        // ---- K-tile T+1 (buf1) ----
        // ph5 (0,0): read A-h0
        load_a<1, 0>(smc, aoff, c0, c1, Afr);
        STAGE_B(1, 0, t3);
        BAR; LGKM0;
        PRIO1; do_mfma<0, 0>(Afr, B0b, acc); PRIO0;
        BAR;
        // ph6 (0,1): read B-h1
        load_b<1, 1>(smc, boff, c0, c1, B1fr);
        STAGE_A(1, 0, t3);
        BAR; LGKM0;
        PRIO1; do_mfma<0, 1>(Afr, B1fr, acc); PRIO0;
        BAR;
        // ph7 (1,1): read A-h1
        load_a<1, 1>(smc, aoff, c0, c1, Afr);
        STAGE_B(1, 1, t3);
        BAR; LGKM0;
        PRIO1; do_mfma<1, 1>(Afr, B1fr, acc); PRIO0;
        BAR;
        // ph8 (1,0): read-ahead B-h0 of tile T+2 (buf0)
        load_b<0, 0>(smc, boff, c0, c1, B0a);
        STAGE_A(1, 1, t3);
        VM4; BAR; LGKM0;
        PRIO1; do_mfma<1, 0>(Afr, B0b, acc); PRIO0;
        BAR;
    }

    // epilogue: D map col=lane&15, row=(lane>>4)*4+j
    const int cr = l4 * 4;
    #pragma unroll
    for (int mh = 0; mh < 2; ++mh)
        #pragma unroll
        for (int mf = 0; mf < 4; ++mf) {
            const long row = brow + mh * 128 + wm * 64 + mf * 16 + cr;
            #pragma unroll
            for (int nh = 0; nh < 2; ++nh)
                #pragma unroll
                for (int nf = 0; nf < 2; ++nf) {
                    const long col = bcol + nh * 128 + wn * 32 + nf * 16 + l15;
                    const f32x4 v = acc[mh * 4 + mf][nh * 2 + nf];
                    float* p = C + row * 4096 + col;
                    p[0]        = v[0];
                    p[4096]     = v[1];
                    p[2 * 4096] = v[2];
                    p[3 * 4096] = v[3];
                }
        }
#undef STAGE_A
#undef STAGE_B
#undef BAR
#undef LGKM0
#undef VM4
#undef VM6
#undef PRIO1
#undef PRIO0
}

extern "C" void kernel_launch(void* const* d_in, const int* in_sizes, int n_in,
                              void* d_out, int out_size, void* d_ws, size_t ws_size,
                              hipStream_t stream) {
    const float* x   = (const float*)d_in[0];
    const float* Wm  = (const float*)d_in[1];
    const float* Wu  = (const float*)d_in[2];
    const float* Wv  = (const float*)d_in[3];
    const float* eps = (const float*)d_in[4];
    float* out = (float*)d_out;

    const int N = in_sizes[2];              // 4096
    const int M = in_sizes[3];              // 4096
    const int B = in_sizes[0] / N;          // 8192

    short* xb = (short*)d_ws;                                  // [B][N] bf16
    short* wt = (short*)((char*)d_ws + (size_t)B * N * 2);     // [M][N] bf16

    cvt_x<<<2048, 256, 0, stream>>>(x, xb, (long)B * N);
    build_wt<<<dim3(M / 64, N / 64), 256, 0, stream>>>(Wm, eps, Wu, Wv, wt, N, M);
    gemm256<<<dim3((B / 256) * (M / 256)), 512, 0, stream>>>(xb, wt, out);
}